// Round 1
// 1417.585 us; speedup vs baseline: 1.3683x; 1.3683x over previous
//
#include <hip/hip_runtime.h>

#define NUSERS 100000
#define NITEMS 50000
#define NNODES 150000
#define HID    128
#define NEDGE  1000000

typedef unsigned int u32;

__device__ __forceinline__ float bflo(u32 u){ return __uint_as_float(u << 16); }
__device__ __forceinline__ float bfhi(u32 u){ return __uint_as_float(u & 0xFFFF0000u); }
// pack two fp32 into bf16x2 (RNE)
__device__ __forceinline__ u32 packbf2(float a, float b){
  u32 ua = __float_as_uint(a), ub = __float_as_uint(b);
  ua += 0x7FFFu + ((ua >> 16) & 1u);
  ub += 0x7FFFu + ((ub >> 16) & 1u);
  return (ua >> 16) | (ub & 0xFFFF0000u);
}

__global__ __launch_bounds__(256) void k_zero(int* __restrict__ p, int n){
  int i = blockIdx.x * 256 + threadIdx.x;
  if (i < n) p[i] = 0;
}

__global__ __launch_bounds__(256) void k_deg(const int* __restrict__ uidx,
                                             const int* __restrict__ iidx,
                                             int* __restrict__ deg){
  int e = blockIdx.x * 256 + threadIdx.x;
  if (e < NEDGE){
    atomicAdd(&deg[uidx[e]], 1);
    atomicAdd(&deg[NUSERS + iidx[e]], 1);
  }
}

__global__ __launch_bounds__(256) void k_dinv(const int* __restrict__ deg,
                                              float* __restrict__ dinv){
  int n = blockIdx.x * 256 + threadIdx.x;
  if (n < NNODES) dinv[n] = rsqrtf(fmaxf((float)deg[n], 1.0f));
}

// ---- 3-kernel exclusive scan of deg -> rp (tile = 1024) ----
__global__ __launch_bounds__(256) void k_scan1(const int* __restrict__ deg,
                                               int* __restrict__ rp,
                                               int* __restrict__ part){
  __shared__ int sm[256];
  int t = threadIdx.x;
  int base = blockIdx.x * 1024 + t * 4;
  int v0 = (base + 0 < NNODES) ? deg[base + 0] : 0;
  int v1 = (base + 1 < NNODES) ? deg[base + 1] : 0;
  int v2 = (base + 2 < NNODES) ? deg[base + 2] : 0;
  int v3 = (base + 3 < NNODES) ? deg[base + 3] : 0;
  sm[t] = v0 + v1 + v2 + v3;
  __syncthreads();
  for (int off = 1; off < 256; off <<= 1){
    int x = (t >= off) ? sm[t - off] : 0;
    __syncthreads();
    sm[t] += x;
    __syncthreads();
  }
  if (t == 255) part[blockIdx.x] = sm[255];
  int run = (t > 0) ? sm[t - 1] : 0;
  if (base + 0 < NNODES) rp[base + 0] = run;
  run += v0;
  if (base + 1 < NNODES) rp[base + 1] = run;
  run += v1;
  if (base + 2 < NNODES) rp[base + 2] = run;
  run += v2;
  if (base + 3 < NNODES) rp[base + 3] = run;
}

__global__ __launch_bounds__(256) void k_scan2(int* __restrict__ part, int nb){
  __shared__ int sm[256];
  int t = threadIdx.x;
  sm[t] = (t < nb) ? part[t] : 0;
  __syncthreads();
  for (int off = 1; off < 256; off <<= 1){
    int x = (t >= off) ? sm[t - off] : 0;
    __syncthreads();
    sm[t] += x;
    __syncthreads();
  }
  int excl = (t > 0) ? sm[t - 1] : 0;
  if (t < nb) part[t] = excl;
}

__global__ __launch_bounds__(256) void k_scan3(int* __restrict__ rp,
                                               const int* __restrict__ part){
  int i = blockIdx.x * 256 + threadIdx.x;
  if (i < NNODES) rp[i] += part[i >> 10];
}

// place both directed edges into CSR-by-dst; payload = src | (t<<18); coefE = dinv[src]
__global__ __launch_bounds__(256) void k_place(const int* __restrict__ uidx,
                                               const int* __restrict__ iidx,
                                               const int* __restrict__ tseq,
                                               const int* __restrict__ rp,
                                               int* __restrict__ cursor,
                                               const float* __restrict__ dinv,
                                               u32* __restrict__ edges,
                                               float* __restrict__ coefE){
  int e = blockIdx.x * 256 + threadIdx.x;
  if (e >= NEDGE) return;
  int u  = uidx[e];
  int it = NUSERS + iidx[e];
  u32 tb = ((u32)tseq[e]) << 18;
  float du = dinv[u], di = dinv[it];
  int p1 = rp[it] + atomicAdd(&cursor[it], 1);  // dst = item, src = user
  edges[p1] = (u32)u | tb;  coefE[p1] = du;
  int p2 = rp[u] + atomicAdd(&cursor[u], 1);    // dst = user, src = item
  edges[p2] = (u32)it | tb; coefE[p2] = di;
}

// x0[n] <- bf16(concat(ue,ie)[n]); out cols [0:128) <- fp32 raw embeddings
__global__ __launch_bounds__(256) void k_init(const float* __restrict__ ue,
                                              const float* __restrict__ ie,
                                              u32* __restrict__ x,
                                              float* __restrict__ out){
  int tid = blockIdx.x * 256 + threadIdx.x;
  int n = tid >> 6, L = tid & 63;
  if (n >= NNODES) return;
  const float* src = (n < NUSERS) ? ue + (size_t)n * HID
                                  : ie + (size_t)(n - NUSERS) * HID;
  float2 v = ((const float2*)src)[L];
  x[(size_t)n * 64 + L] = packbf2(v.x, v.y);
  ((float2*)(out + (size_t)n * 512))[L] = v;
}

// Layer-invariant time aggregate: T[n] = sum_e dinv[src]*tt[t_e], stored in
// out[n][384:512) (layer 3 reads it during gather, then overwrites it at store).
__global__ __launch_bounds__(512) void k_time(const float* __restrict__ tt,
                                              const int* __restrict__ rp,
                                              const int* __restrict__ deg,
                                              const u32* __restrict__ edges,
                                              const float* __restrict__ coefE,
                                              float* __restrict__ out){
  int wv = threadIdx.x >> 6;
  int L  = threadIdx.x & 63;
  int n  = blockIdx.x * 8 + wv;   // grid exact
  int start = rp[n];
  int cnt   = deg[n];
  float a0 = 0.f, a1 = 0.f;
  for (int base = 0; base < cnt; base += 64){
    int m = cnt - base; if (m > 64) m = 64;
    u32 pe = 0; float cf = 0.f;
    if (L < m){ pe = edges[start + base + L]; cf = coefE[start + base + L]; }
    int j = 0;
    for (; j + 2 <= m; j += 2){
      u32 t0 = __shfl(pe, j) >> 18;
      u32 t1 = __shfl(pe, j + 1) >> 18;
      float c0 = __shfl(cf, j);
      float c1 = __shfl(cf, j + 1);
      float2 v0 = ((const float2*)(tt + (size_t)t0 * HID))[L];
      float2 v1 = ((const float2*)(tt + (size_t)t1 * HID))[L];
      a0 = fmaf(v0.x, c0, a0); a1 = fmaf(v0.y, c0, a1);
      a0 = fmaf(v1.x, c1, a0); a1 = fmaf(v1.y, c1, a1);
    }
    if (j < m){
      u32 t0 = __shfl(pe, j) >> 18;
      float c0 = __shfl(cf, j);
      float2 v0 = ((const float2*)(tt + (size_t)t0 * HID))[L];
      a0 = fmaf(v0.x, c0, a0); a1 = fmaf(v0.y, c0, a1);
    }
  }
  ((float2*)(out + (size_t)n * 512 + 384))[L] = make_float2(a0, a1);
}

// Fused layer: 1024 threads = 16 waves = 16 nodes/block.
// LDS = 64KB W + 8KB agg = 72KB -> 2 blocks/CU = 32 waves/CU (100% occupancy).
//   agg = dinv[n] * (sum_e coef_e * xin[src] + T[n])   (T read from out[:,384:512))
//   h   = leaky(agg @ W + b); xout <- bf16(h); out[:, colOff:+128) <- l2norm(h)
__global__ __launch_bounds__(1024, 8) void k_layer(
    const u32* __restrict__ xin,   // bf16x2 packed [NNODES][64]
    const float* __restrict__ dinv,
    const int* __restrict__ rp,
    const int* __restrict__ deg,
    const u32* __restrict__ edges,
    const float* __restrict__ coefE,
    const float* __restrict__ Wl,  // [128][128] row-major (k, col)
    const float* __restrict__ bl,  // [128]
    u32* __restrict__ xout,
    float* __restrict__ out,       // [NNODES][512]
    int colOff)
{
  __shared__ float Ws[HID * HID];   // 64 KB
  __shared__ float aggS[16][HID];   // 8 KB
  {
    const float4* Wg = (const float4*)Wl;
    float4* Wv = (float4*)Ws;
    #pragma unroll
    for (int i = 0; i < 4; i++) Wv[threadIdx.x + 1024 * i] = Wg[threadIdx.x + 1024 * i];
  }
  __syncthreads();   // Ws visible; aggS needs no barrier (same-wave row use only)

  int wv = threadIdx.x >> 6;
  int L  = threadIdx.x & 63;
  int n  = blockIdx.x * 16 + wv;   // grid exact (150000/16 = 9375) -> always valid

  int start = rp[n];
  int cnt   = deg[n];
  // start from the precomputed time aggregate
  float2 Tv = ((const float2*)(out + (size_t)n * 512 + 384))[L];
  float a0 = Tv.x, a1 = Tv.y;

  for (int base = 0; base < cnt; base += 64){
    int m = cnt - base; if (m > 64) m = 64;
    u32 pe = 0; float cf = 0.f;
    if (L < m){ pe = edges[start + base + L]; cf = coefE[start + base + L]; }
    int j = 0;
    for (; j + 2 <= m; j += 2){                  // 2 independent load chains
      u32 q0 = __shfl(pe, j);
      u32 q1 = __shfl(pe, j + 1);
      float c0 = __shfl(cf, j);
      float c1 = __shfl(cf, j + 1);
      u32 s0 = q0 & 0x3FFFFu;
      u32 s1 = q1 & 0x3FFFFu;
      u32 v0 = xin[(size_t)s0 * 64 + L];
      u32 v1 = xin[(size_t)s1 * 64 + L];
      a0 = fmaf(bflo(v0), c0, a0); a1 = fmaf(bfhi(v0), c0, a1);
      a0 = fmaf(bflo(v1), c1, a0); a1 = fmaf(bfhi(v1), c1, a1);
    }
    if (j < m){
      u32 q0 = __shfl(pe, j);
      float c0 = __shfl(cf, j);
      u32 s0 = q0 & 0x3FFFFu;
      u32 v0 = xin[(size_t)s0 * 64 + L];
      a0 = fmaf(bflo(v0), c0, a0); a1 = fmaf(bfhi(v0), c0, a1);
    }
  }
  float sc = dinv[n];
  aggS[wv][2 * L]     = a0 * sc;
  aggS[wv][2 * L + 1] = a1 * sc;
  // no barrier: each wave reads only its own aggS row (same-wave DS order)

  float acc0 = 0.f, acc1 = 0.f;
  #pragma unroll 4
  for (int k = 0; k < HID; k += 4){
    float4 a4 = *(const float4*)(&aggS[wv][k]);       // broadcast b128
    float2 w0 = ((const float2*)(Ws + (k + 0) * HID))[L];
    float2 w1 = ((const float2*)(Ws + (k + 1) * HID))[L];
    float2 w2 = ((const float2*)(Ws + (k + 2) * HID))[L];
    float2 w3 = ((const float2*)(Ws + (k + 3) * HID))[L];
    acc0 = fmaf(a4.x, w0.x, acc0); acc1 = fmaf(a4.x, w0.y, acc1);
    acc0 = fmaf(a4.y, w1.x, acc0); acc1 = fmaf(a4.y, w1.y, acc1);
    acc0 = fmaf(a4.z, w2.x, acc0); acc1 = fmaf(a4.z, w2.y, acc1);
    acc0 = fmaf(a4.w, w3.x, acc0); acc1 = fmaf(a4.w, w3.y, acc1);
  }
  float2 bb = ((const float2*)bl)[L];
  acc0 += bb.x;
  acc1 += bb.y;
  acc0 = (acc0 > 0.f) ? acc0 : 0.2f * acc0;
  acc1 = (acc1 > 0.f) ? acc1 : 0.2f * acc1;

  xout[(size_t)n * 64 + L] = packbf2(acc0, acc1);  // unnormalized h -> next layer

  float ss = fmaf(acc0, acc0, acc1 * acc1);
  #pragma unroll
  for (int off = 1; off < 64; off <<= 1) ss += __shfl_xor(ss, off);
  float inv = 1.0f / fmaxf(sqrtf(ss), 1e-12f);
  ((float2*)(out + (size_t)n * 512 + colOff))[L] = make_float2(acc0 * inv, acc1 * inv);
}

extern "C" void kernel_launch(void* const* d_in, const int* in_sizes, int n_in,
                              void* d_out, int out_size, void* d_ws, size_t ws_size,
                              hipStream_t stream){
  const float* ue = (const float*)d_in[0];  // [100000,128] fp32
  const float* ie = (const float*)d_in[1];  // [50000,128]  fp32
  const float* tt = (const float*)d_in[2];  // [512,128]    fp32
  const float* W  = (const float*)d_in[3];  // [3,128,128]  fp32
  const float* b  = (const float*)d_in[4];  // [3,128]      fp32
  const int* uidx = (const int*)d_in[5];
  const int* iidx = (const int*)d_in[6];
  const int* tseq = (const int*)d_in[7];
  float* out = (float*)d_out;               // [150000,512] fp32

  char* wsp = (char*)d_ws;
  size_t off = 0;
  auto alloc = [&](size_t bytes) -> void* {
    void* p = wsp + off;
    off = (off + bytes + 255) & ~(size_t)255;
    return p;
  };
  int*   degcur = (int*)  alloc((size_t)2 * NNODES * 4);   // deg | cursor (one zero pass)
  int*   deg    = degcur;
  int*   cursor = degcur + NNODES;
  float* dinv   = (float*)alloc((size_t)NNODES * 4);
  int*   rp     = (int*)  alloc((size_t)NNODES * 4);
  int*   part   = (int*)  alloc(256 * 4);
  u32*   edges  = (u32*)  alloc((size_t)2 * NEDGE * 4);
  float* coefE  = (float*)alloc((size_t)2 * NEDGE * 4);    // dinv[src] per placed edge
  u32*   x0     = (u32*)  alloc((size_t)NNODES * 64 * 4);  // bf16x2 packed
  u32*   x1     = (u32*)  alloc((size_t)NNODES * 64 * 4);
  // total ws use: ~96 MB

  const int nbZ = (2 * NNODES + 255) / 256; // 1172
  const int nbN = (NNODES + 255) / 256;     // 587
  const int nbE = (NEDGE + 255) / 256;      // 3907
  const int nbT = (NNODES + 1023) / 1024;   // 147
  const int nbI = NNODES * 64 / 256;        // 37500 (exact)
  const int nbM = NNODES / 8;               // 18750 (exact) for k_time
  const int nbL = NNODES / 16;              // 9375  (exact) for k_layer

  k_zero<<<nbZ, 256, 0, stream>>>(degcur, 2 * NNODES);
  k_deg<<<nbE, 256, 0, stream>>>(uidx, iidx, deg);
  k_dinv<<<nbN, 256, 0, stream>>>(deg, dinv);
  k_scan1<<<nbT, 256, 0, stream>>>(deg, rp, part);
  k_scan2<<<1, 256, 0, stream>>>(part, nbT);
  k_scan3<<<nbN, 256, 0, stream>>>(rp, part);
  k_place<<<nbE, 256, 0, stream>>>(uidx, iidx, tseq, rp, cursor, dinv, edges, coefE);
  k_init<<<nbI, 256, 0, stream>>>(ue, ie, x0, out);
  k_time<<<nbM, 512, 0, stream>>>(tt, rp, deg, edges, coefE, out);

  k_layer<<<nbL, 1024, 0, stream>>>(x0, dinv, rp, deg, edges, coefE,
                                    W + 0 * HID * HID, b + 0 * HID, x1, out, 1 * HID);
  k_layer<<<nbL, 1024, 0, stream>>>(x1, dinv, rp, deg, edges, coefE,
                                    W + 1 * HID * HID, b + 1 * HID, x0, out, 2 * HID);
  k_layer<<<nbL, 1024, 0, stream>>>(x0, dinv, rp, deg, edges, coefE,
                                    W + 2 * HID * HID, b + 2 * HID, x1, out, 3 * HID);
}

// Round 3
// 1068.346 us; speedup vs baseline: 1.8156x; 1.3269x over previous
//
#include <hip/hip_runtime.h>

#define NUSERS 100000
#define NITEMS 50000
#define NNODES 150000
#define HID    128
#define NEDGE  1000000

typedef unsigned int u32;
using s16x8 = __attribute__((ext_vector_type(8))) short;
using f32x4 = __attribute__((ext_vector_type(4))) float;

__device__ __forceinline__ float bflo(u32 u){ return __uint_as_float(u << 16); }
__device__ __forceinline__ float bfhi(u32 u){ return __uint_as_float(u & 0xFFFF0000u); }
// pack two fp32 into bf16x2 (RNE)
__device__ __forceinline__ u32 packbf2(float a, float b){
  u32 ua = __float_as_uint(a), ub = __float_as_uint(b);
  ua += 0x7FFFu + ((ua >> 16) & 1u);
  ub += 0x7FFFu + ((ub >> 16) & 1u);
  return (ua >> 16) | (ub & 0xFFFF0000u);
}

__global__ __launch_bounds__(256) void k_zero(int* __restrict__ p, int n){
  int i = blockIdx.x * 256 + threadIdx.x;
  if (i < n) p[i] = 0;
}

__global__ __launch_bounds__(256) void k_deg(const int* __restrict__ uidx,
                                             const int* __restrict__ iidx,
                                             int* __restrict__ deg){
  int e = blockIdx.x * 256 + threadIdx.x;
  if (e < NEDGE){
    atomicAdd(&deg[uidx[e]], 1);
    atomicAdd(&deg[NUSERS + iidx[e]], 1);
  }
}

__global__ __launch_bounds__(256) void k_dinv(const int* __restrict__ deg,
                                              float* __restrict__ dinv){
  int n = blockIdx.x * 256 + threadIdx.x;
  if (n < NNODES) dinv[n] = rsqrtf(fmaxf((float)deg[n], 1.0f));
}

// ---- 3-kernel exclusive scan of deg -> rp (tile = 1024) ----
__global__ __launch_bounds__(256) void k_scan1(const int* __restrict__ deg,
                                               int* __restrict__ rp,
                                               int* __restrict__ part){
  __shared__ int sm[256];
  int t = threadIdx.x;
  int base = blockIdx.x * 1024 + t * 4;
  int v0 = (base + 0 < NNODES) ? deg[base + 0] : 0;
  int v1 = (base + 1 < NNODES) ? deg[base + 1] : 0;
  int v2 = (base + 2 < NNODES) ? deg[base + 2] : 0;
  int v3 = (base + 3 < NNODES) ? deg[base + 3] : 0;
  sm[t] = v0 + v1 + v2 + v3;
  __syncthreads();
  for (int off = 1; off < 256; off <<= 1){
    int x = (t >= off) ? sm[t - off] : 0;
    __syncthreads();
    sm[t] += x;
    __syncthreads();
  }
  if (t == 255) part[blockIdx.x] = sm[255];
  int run = (t > 0) ? sm[t - 1] : 0;
  if (base + 0 < NNODES) rp[base + 0] = run;
  run += v0;
  if (base + 1 < NNODES) rp[base + 1] = run;
  run += v1;
  if (base + 2 < NNODES) rp[base + 2] = run;
  run += v2;
  if (base + 3 < NNODES) rp[base + 3] = run;
}

__global__ __launch_bounds__(256) void k_scan2(int* __restrict__ part, int nb){
  __shared__ int sm[256];
  int t = threadIdx.x;
  sm[t] = (t < nb) ? part[t] : 0;
  __syncthreads();
  for (int off = 1; off < 256; off <<= 1){
    int x = (t >= off) ? sm[t - off] : 0;
    __syncthreads();
    sm[t] += x;
    __syncthreads();
  }
  int excl = (t > 0) ? sm[t - 1] : 0;
  if (t < nb) part[t] = excl;
}

__global__ __launch_bounds__(256) void k_scan3(int* __restrict__ rp,
                                               const int* __restrict__ part){
  int i = blockIdx.x * 256 + threadIdx.x;
  if (i < NNODES) rp[i] += part[i >> 10];
}

// place both directed edges into CSR-by-dst; payload = src | (t<<18); coefE = dinv[src]
__global__ __launch_bounds__(256) void k_place(const int* __restrict__ uidx,
                                               const int* __restrict__ iidx,
                                               const int* __restrict__ tseq,
                                               const int* __restrict__ rp,
                                               int* __restrict__ cursor,
                                               const float* __restrict__ dinv,
                                               u32* __restrict__ edges,
                                               float* __restrict__ coefE){
  int e = blockIdx.x * 256 + threadIdx.x;
  if (e >= NEDGE) return;
  int u  = uidx[e];
  int it = NUSERS + iidx[e];
  u32 tb = ((u32)tseq[e]) << 18;
  float du = dinv[u], di = dinv[it];
  int p1 = rp[it] + atomicAdd(&cursor[it], 1);  // dst = item, src = user
  edges[p1] = (u32)u | tb;  coefE[p1] = du;
  int p2 = rp[u] + atomicAdd(&cursor[u], 1);    // dst = user, src = item
  edges[p2] = (u32)it | tb; coefE[p2] = di;
}

// x0[n] <- bf16(concat(ue,ie)[n]); out cols [0:128) <- fp32 raw embeddings
__global__ __launch_bounds__(256) void k_init(const float* __restrict__ ue,
                                              const float* __restrict__ ie,
                                              u32* __restrict__ x,
                                              float* __restrict__ out){
  int tid = blockIdx.x * 256 + threadIdx.x;
  int n = tid >> 6, L = tid & 63;
  if (n >= NNODES) return;
  const float* src = (n < NUSERS) ? ue + (size_t)n * HID
                                  : ie + (size_t)(n - NUSERS) * HID;
  float2 v = ((const float2*)src)[L];
  x[(size_t)n * 64 + L] = packbf2(v.x, v.y);
  ((float2*)(out + (size_t)n * 512))[L] = v;
}

// Split W into bf16 hi + bf16 residual, TRANSPOSED to [layer][col][k] (u32-packed k-pairs).
__global__ __launch_bounds__(256) void k_wprep(const float* __restrict__ W,
                                               u32* __restrict__ WhiG,
                                               u32* __restrict__ WloG){
  int tid = blockIdx.x * 256 + threadIdx.x;   // 0 .. 24575 = 3*128*64
  int l   = tid >> 13;
  int rem = tid & 8191;
  int c   = rem >> 6;          // output col 0..127
  int kp  = rem & 63;          // k pair
  const float* Wl = W + l * 16384;
  float w0 = Wl[(2 * kp + 0) * 128 + c];
  float w1 = Wl[(2 * kp + 1) * 128 + c];
  u32 hi = packbf2(w0, w1);
  float r0 = w0 - bflo(hi), r1 = w1 - bfhi(hi);
  WhiG[tid] = hi;                    // [l][c][kp]
  WloG[tid] = packbf2(r0, r1);
}

// Fused layer: 1024 threads = 16 waves = 16 nodes/block.
// LDS: Wt bf16 hi+lo [2][128][136pad] = 69632 B + union(aggS hi/lo bf16 | hS f32) 8704 B
//      = 78336 B -> 2 blocks/CU = 32 waves/CU.
// Phase 1: stage Wt, per-wave edge gather (agg in fp32; MODE 1 also accumulates
//          time-term T and writes it to out[:,384:512)).
// Phase 2: 8 waves compute h = agg @ W via split-bf16 MFMA (Ahi*Whi + Alo*Whi + Ahi*Wlo).
// Phase 3: per-wave epilogue: +bias, leaky, bf16 xout, l2norm -> out.
template<int MODE>   // 1 = layer 1 (fuse time gather, write T); 0 = read T
__global__ __launch_bounds__(1024, 8) void k_layer_t(
    const u32* __restrict__ xin,   // bf16x2 packed [NNODES][64]
    const float* __restrict__ tt,  // [512][128] (MODE 1 only)
    const float* __restrict__ dinv,
    const int* __restrict__ rp,
    const int* __restrict__ deg,
    const u32* __restrict__ edges,
    const float* __restrict__ coefE,
    const u32* __restrict__ whi,   // [128][64] u32 bf16-pairs, transposed W
    const u32* __restrict__ wlo,
    const float* __restrict__ bl,  // [128]
    u32* __restrict__ xout,
    float* __restrict__ out,       // [NNODES][512]
    int colOff)
{
  __shared__ u32 WtS[2 * 128 * 68];    // hi | lo, rows padded to 68 dwords
  __shared__ u32 unionS[2 * 16 * 68];  // aggS hi | lo; later hS f32 [16][130]

  // stage Wt (coalesced 32B/thread per half)
  {
    int t = threadIdx.x;
    int r = t >> 3, seg = t & 7;
    const uint4* sh = (const uint4*)(whi + r * 64 + seg * 8);
    const uint4* sl = (const uint4*)(wlo + r * 64 + seg * 8);
    uint4* dh = (uint4*)(WtS + r * 68 + seg * 8);
    uint4* dl = (uint4*)(WtS + 128 * 68 + r * 68 + seg * 8);
    uint4 a = sh[0], b = sh[1], c = sl[0], d = sl[1];
    dh[0] = a; dh[1] = b;
    dl[0] = c; dl[1] = d;
  }

  int wv = threadIdx.x >> 6;
  int L  = threadIdx.x & 63;
  int n  = blockIdx.x * 16 + wv;   // grid exact (150000/16 = 9375)

  int start = rp[n];
  int cnt   = deg[n];
  float a0, a1, t0, t1;
  if (MODE == 1){ a0 = 0.f; a1 = 0.f; t0 = 0.f; t1 = 0.f; }
  else {
    float2 Tv = ((const float2*)(out + (size_t)n * 512 + 384))[L];
    a0 = Tv.x; a1 = Tv.y; t0 = 0.f; t1 = 0.f;
  }

  for (int base = 0; base < cnt; base += 64){
    int m = cnt - base; if (m > 64) m = 64;
    u32 pe = 0; float cf = 0.f;
    if (L < m){ pe = edges[start + base + L]; cf = coefE[start + base + L]; }
    int j = 0;
    for (; j + 2 <= m; j += 2){                  // 2 independent load chains
      u32 q0 = __shfl(pe, j);
      u32 q1 = __shfl(pe, j + 1);
      float c0 = __shfl(cf, j);
      float c1 = __shfl(cf, j + 1);
      u32 s0 = q0 & 0x3FFFFu;
      u32 s1 = q1 & 0x3FFFFu;
      u32 v0 = xin[(size_t)s0 * 64 + L];
      u32 v1 = xin[(size_t)s1 * 64 + L];
      if (MODE == 1){
        float2 tv0 = ((const float2*)(tt + (size_t)(q0 >> 18) * HID))[L];
        float2 tv1 = ((const float2*)(tt + (size_t)(q1 >> 18) * HID))[L];
        t0 = fmaf(tv0.x, c0, t0); t1 = fmaf(tv0.y, c0, t1);
        t0 = fmaf(tv1.x, c1, t0); t1 = fmaf(tv1.y, c1, t1);
      }
      a0 = fmaf(bflo(v0), c0, a0); a1 = fmaf(bfhi(v0), c0, a1);
      a0 = fmaf(bflo(v1), c1, a0); a1 = fmaf(bfhi(v1), c1, a1);
    }
    if (j < m){
      u32 q0 = __shfl(pe, j);
      float c0 = __shfl(cf, j);
      u32 s0 = q0 & 0x3FFFFu;
      u32 v0 = xin[(size_t)s0 * 64 + L];
      if (MODE == 1){
        float2 tv0 = ((const float2*)(tt + (size_t)(q0 >> 18) * HID))[L];
        t0 = fmaf(tv0.x, c0, t0); t1 = fmaf(tv0.y, c0, t1);
      }
      a0 = fmaf(bflo(v0), c0, a0); a1 = fmaf(bfhi(v0), c0, a1);
    }
  }
  if (MODE == 1){
    ((float2*)(out + (size_t)n * 512 + 384))[L] = make_float2(t0, t1);  // T for layers 2,3
    a0 += t0; a1 += t1;
  }
  float sc = dinv[n];
  float s0 = a0 * sc, s1 = a1 * sc;
  // split agg into bf16 hi + bf16 residual
  u32 ph = packbf2(s0, s1);
  float r0 = s0 - bflo(ph), r1 = s1 - bfhi(ph);
  unionS[wv * 68 + L] = ph;
  unionS[16 * 68 + wv * 68 + L] = packbf2(r0, r1);

  __syncthreads();   // aggS + WtS ready

  int ml = L & 15, kg = L >> 4;
  f32x4 D = {0.f, 0.f, 0.f, 0.f};
  if (wv < 8){
    const u32* Ah = unionS + ml * 68 + kg * 4;
    const u32* Al = Ah + 16 * 68;
    const u32* Bh = WtS + (wv * 16 + ml) * 68 + kg * 4;
    const u32* Bl = Bh + 128 * 68;
    #pragma unroll
    for (int ks = 0; ks < 4; ks++){
      s16x8 ah = *(const s16x8*)(Ah + ks * 16);
      s16x8 al = *(const s16x8*)(Al + ks * 16);
      s16x8 bh = *(const s16x8*)(Bh + ks * 16);
      s16x8 bb = *(const s16x8*)(Bl + ks * 16);
      D = __builtin_amdgcn_mfma_f32_16x16x32_bf16(ah, bh, D, 0, 0, 0);
      D = __builtin_amdgcn_mfma_f32_16x16x32_bf16(al, bh, D, 0, 0, 0);
      D = __builtin_amdgcn_mfma_f32_16x16x32_bf16(ah, bb, D, 0, 0, 0);
    }
  }
  __syncthreads();   // all aggS reads done before hS overwrite
  if (wv < 8){
    float* hS = (float*)unionS;        // [16][130]
    #pragma unroll
    for (int i = 0; i < 4; i++){
      int row = kg * 4 + i;            // C/D layout: col=lane&15, row=(lane>>4)*4+i
      hS[row * 130 + wv * 16 + ml] = D[i];
    }
  }
  __syncthreads();

  const float* hS = (const float*)unionS;
  float2 h2 = ((const float2*)(hS + wv * 130))[L];
  float2 bb2 = ((const float2*)bl)[L];
  float acc0 = h2.x + bb2.x;
  float acc1 = h2.y + bb2.y;
  acc0 = (acc0 > 0.f) ? acc0 : 0.2f * acc0;
  acc1 = (acc1 > 0.f) ? acc1 : 0.2f * acc1;

  xout[(size_t)n * 64 + L] = packbf2(acc0, acc1);  // unnormalized h -> next layer

  float ss = fmaf(acc0, acc0, acc1 * acc1);
  #pragma unroll
  for (int off = 1; off < 64; off <<= 1) ss += __shfl_xor(ss, off);
  float inv = 1.0f / fmaxf(sqrtf(ss), 1e-12f);
  ((float2*)(out + (size_t)n * 512 + colOff))[L] = make_float2(acc0 * inv, acc1 * inv);
}

extern "C" void kernel_launch(void* const* d_in, const int* in_sizes, int n_in,
                              void* d_out, int out_size, void* d_ws, size_t ws_size,
                              hipStream_t stream){
  const float* ue = (const float*)d_in[0];  // [100000,128] fp32
  const float* ie = (const float*)d_in[1];  // [50000,128]  fp32
  const float* tt = (const float*)d_in[2];  // [512,128]    fp32
  const float* W  = (const float*)d_in[3];  // [3,128,128]  fp32
  const float* b  = (const float*)d_in[4];  // [3,128]      fp32
  const int* uidx = (const int*)d_in[5];
  const int* iidx = (const int*)d_in[6];
  const int* tseq = (const int*)d_in[7];
  float* out = (float*)d_out;               // [150000,512] fp32

  char* wsp = (char*)d_ws;
  size_t off = 0;
  auto alloc = [&](size_t bytes) -> void* {
    void* p = wsp + off;
    off = (off + bytes + 255) & ~(size_t)255;
    return p;
  };
  int*   degcur = (int*)  alloc((size_t)2 * NNODES * 4);   // deg | cursor
  int*   deg    = degcur;
  int*   cursor = degcur + NNODES;
  float* dinv   = (float*)alloc((size_t)NNODES * 4);
  int*   rp     = (int*)  alloc((size_t)NNODES * 4);
  int*   part   = (int*)  alloc(256 * 4);
  u32*   edges  = (u32*)  alloc((size_t)2 * NEDGE * 4);
  float* coefE  = (float*)alloc((size_t)2 * NEDGE * 4);
  u32*   x0     = (u32*)  alloc((size_t)NNODES * 64 * 4);  // bf16x2 packed
  u32*   x1     = (u32*)  alloc((size_t)NNODES * 64 * 4);
  u32*   whiG   = (u32*)  alloc((size_t)3 * 128 * 64 * 4); // transposed bf16 W hi
  u32*   wloG   = (u32*)  alloc((size_t)3 * 128 * 64 * 4); // residual
  // safety: if the workspace is smaller than our footprint, fail visibly
  // (wrong output) instead of faulting the container with OOB writes.
  if (off > ws_size) return;

  const int nbZ = (2 * NNODES + 255) / 256; // 1172
  const int nbN = (NNODES + 255) / 256;     // 587
  const int nbE = (NEDGE + 255) / 256;      // 3907
  const int nbT = (NNODES + 1023) / 1024;   // 147
  const int nbI = NNODES * 64 / 256;        // 37500 (exact)
  const int nbL = NNODES / 16;              // 9375  (exact)
  const int nbW = 3 * 128 * 64 / 256;       // 96    (exact)

  k_zero<<<nbZ, 256, 0, stream>>>(degcur, 2 * NNODES);
  k_wprep<<<nbW, 256, 0, stream>>>(W, whiG, wloG);
  k_deg<<<nbE, 256, 0, stream>>>(uidx, iidx, deg);
  k_dinv<<<nbN, 256, 0, stream>>>(deg, dinv);
  k_scan1<<<nbT, 256, 0, stream>>>(deg, rp, part);
  k_scan2<<<1, 256, 0, stream>>>(part, nbT);
  k_scan3<<<nbN, 256, 0, stream>>>(rp, part);
  k_place<<<nbE, 256, 0, stream>>>(uidx, iidx, tseq, rp, cursor, dinv, edges, coefE);
  k_init<<<nbI, 256, 0, stream>>>(ue, ie, x0, out);

  k_layer_t<1><<<nbL, 1024, 0, stream>>>(x0, tt, dinv, rp, deg, edges, coefE,
                                         whiG + 0 * 8192, wloG + 0 * 8192,
                                         b + 0 * HID, x1, out, 1 * HID);
  k_layer_t<0><<<nbL, 1024, 0, stream>>>(x1, tt, dinv, rp, deg, edges, coefE,
                                         whiG + 1 * 8192, wloG + 1 * 8192,
                                         b + 1 * HID, x0, out, 2 * HID);
  k_layer_t<0><<<nbL, 1024, 0, stream>>>(x0, tt, dinv, rp, deg, edges, coefE,
                                         whiG + 2 * 8192, wloG + 2 * 8192,
                                         b + 2 * HID, x1, out, 3 * HID);
}